// Round 7
// baseline (3262.908 us; speedup 1.0000x reference)
//
#include <hip/hip_runtime.h>
#include <hip/hip_bf16.h>

typedef float f32x4 __attribute__((ext_vector_type(4)));

#define E_DIM 1024    // embed dim (output cols)
#define F_DIM 4096    // ffn dim
#define ROWS  16384   // B*S
#define NBLK  2048    // ALL co-resident: 8 blocks/CU x 256 CU (<=64 VGPR, 0 LDS)
#define NPROD 64      // producer blocks; each computes 16 o-elements
#define FLAG_TARGET (NPROD * 4)   // one arrival per producer wave

// Single fused kernel, hand-rolled producer->consumer dependency.
//   o[e] = sum_g w_out[e,g] * relu( sum_f w2[g,f] * q[f] ),  then
//   out[r,:] = o[:] for all 16384 rows.
// q = analytic 4-qubit circuit expvals; x/w1 are a dead path (RZ on |0> is a
// global phase) -> 64 MiB of input never read.
// Deadlock safety (G16): grid is exactly 2048 blocks with launch_bounds
// (256,8) -> every block is co-resident; producers make progress regardless
// of dispatch order. Cross-XCD visibility: release stores/adds by producers,
// acquire flag load + relaxed AGENT-scope o loads by consumers (per-XCD L2s
// are not coherent; agent-scope ops go through the shared level).
__global__ __launch_bounds__(256, 8) void qff_fused(
    const float* __restrict__ w2,       // (4096, 4) row-major
    const float* __restrict__ wout,     // (1024, 4096) row-major
    const float* __restrict__ params,   // (4,)
    float* __restrict__ o,              // (1024,) in d_ws
    unsigned int* __restrict__ flag,    // 1 u32 in d_ws (memset to 0 each call)
    float* __restrict__ out)            // (16384, 1024)
{
    const int t = threadIdx.x;
    const int bid = blockIdx.x;

    // ---- producer phase: blocks 0..63 compute o[bid*16 .. bid*16+16) ----
    if (bid < NPROD) {
        const int wave = t >> 6;
        const int lane = t & 63;

        const float c0 = cosf(params[0]);
        const float c1 = cosf(params[1]);
        const float c2 = cosf(params[2]);
        const float c3 = cosf(params[3]);
        const float q0 = c1 * c2 * c3;
        const float q1 = c0 * c1;
        const float q2 = q1 * c2;
        const float q3 = q2 * c3;

        const f32x4* w2v = reinterpret_cast<const f32x4*>(w2);
#pragma unroll
        for (int i = 0; i < 4; ++i) {
            const int e = bid * 16 + wave * 4 + i;
            const f32x4* wrow = reinterpret_cast<const f32x4*>(wout + (size_t)e * F_DIM);
            float s = 0.0f;
#pragma unroll
            for (int j = 0; j < 16; ++j) {
                const int g4 = j * 64 + lane;
                f32x4 a  = __builtin_nontemporal_load(&wrow[g4]);  // read-once
                f32x4 r0 = w2v[4 * g4 + 0];                        // L2-resident
                f32x4 r1 = w2v[4 * g4 + 1];
                f32x4 r2 = w2v[4 * g4 + 2];
                f32x4 r3 = w2v[4 * g4 + 3];
                float h0 = fmaxf(r0.x * q0 + r0.y * q1 + r0.z * q2 + r0.w * q3, 0.0f);
                float h1 = fmaxf(r1.x * q0 + r1.y * q1 + r1.z * q2 + r1.w * q3, 0.0f);
                float h2 = fmaxf(r2.x * q0 + r2.y * q1 + r2.z * q2 + r2.w * q3, 0.0f);
                float h3 = fmaxf(r3.x * q0 + r3.y * q1 + r3.z * q2 + r3.w * q3, 0.0f);
                s += a.x * h0 + a.y * h1 + a.z * h2 + a.w * h3;
            }
#pragma unroll
            for (int off = 32; off > 0; off >>= 1) s += __shfl_down(s, off);
            if (lane == 0)
                __hip_atomic_store(&o[e], s, __ATOMIC_RELEASE, __HIP_MEMORY_SCOPE_AGENT);
        }
        if (lane == 0)
            __hip_atomic_fetch_add(flag, 1u, __ATOMIC_RELEASE, __HIP_MEMORY_SCOPE_AGENT);
    }

    // ---- wait for all 256 producer-wave arrivals ----
    if (t == 0) {
        while (__hip_atomic_load(flag, __ATOMIC_ACQUIRE, __HIP_MEMORY_SCOPE_AGENT)
               < FLAG_TARGET) {
            __builtin_amdgcn_s_sleep(8);
        }
    }
    __syncthreads();

    // ---- consumer phase: every block broadcasts o into its 8 rows ----
    // thread t owns column-float4 t; agent-scope loads -> never-stale
    float v0 = __hip_atomic_load(&o[t * 4 + 0], __ATOMIC_RELAXED, __HIP_MEMORY_SCOPE_AGENT);
    float v1 = __hip_atomic_load(&o[t * 4 + 1], __ATOMIC_RELAXED, __HIP_MEMORY_SCOPE_AGENT);
    float v2 = __hip_atomic_load(&o[t * 4 + 2], __ATOMIC_RELAXED, __HIP_MEMORY_SCOPE_AGENT);
    float v3 = __hip_atomic_load(&o[t * 4 + 3], __ATOMIC_RELAXED, __HIP_MEMORY_SCOPE_AGENT);
    f32x4 v = {v0, v1, v2, v3};

    f32x4* out4 = reinterpret_cast<f32x4*>(out);
    const int r0 = bid * (ROWS / NBLK);             // 8 rows per block
#pragma unroll
    for (int k = 0; k < ROWS / NBLK; ++k) {
        // each wave stores 1 KB contiguous; block stores 4 KB/iter
        __builtin_nontemporal_store(v, &out4[(size_t)(r0 + k) * (E_DIM / 4) + t]);
    }
}

extern "C" void kernel_launch(void* const* d_in, const int* in_sizes, int n_in,
                              void* d_out, int out_size, void* d_ws, size_t ws_size,
                              hipStream_t stream) {
    // inputs (setup_inputs order): x, w1, w2, w_out, params — x/w1 never read.
    const float* w2     = (const float*)d_in[2];
    const float* w_out  = (const float*)d_in[3];
    const float* params = (const float*)d_in[4];
    float* o = (float*)d_ws;                          // 1024 floats
    unsigned int* flag = (unsigned int*)((char*)d_ws + E_DIM * sizeof(float));
    float* out = (float*)d_out;

    hipMemsetAsync(flag, 0, sizeof(unsigned int), stream);   // reset arrivals
    qff_fused<<<NBLK, 256, 0, stream>>>(w2, w_out, params, o, flag, out);
}

// Round 8
// 121.566 us; speedup vs baseline: 26.8407x; 26.8407x over previous
//
#include <hip/hip_runtime.h>
#include <hip/hip_bf16.h>

typedef float f32x4 __attribute__((ext_vector_type(4)));

#define E_DIM 1024    // embed dim (output cols)
#define F_DIM 4096    // ffn dim
#define ROWS  16384   // B*S
#define NBLK  2048    // ALL co-resident: 8 blocks/CU x 256 CU (32 VGPR, 0 LDS)
#define NPROD 64      // producer blocks; each computes 16 o-elements

// Single fused kernel, hand-rolled producer->consumer dependency.
//   o[e] = sum_g w_out[e,g] * relu( sum_f w2[g,f] * q[f] ),  then
//   out[r,:] = o[:] for all 16384 rows.
// q = analytic 4-qubit circuit expvals; x/w1 are a dead path (RZ on |0> is a
// global phase) -> 64 MiB of input never read.
//
// R7 lesson: agent-scope atomic LOADS of o (2.1M to the same 4 KB) serialize
// at the coherence point -> 3.3 ms. This version: ONE atomicAdd per producer
// block (64 total), relaxed spin polls, ONE acquire fence, then plain cached
// vector loads of o. Deadlock safety (G16): exactly 2048 blocks at
// launch_bounds(256,8) -> all co-resident; producers progress regardless of
// dispatch order (verified: R7 completed, never deadlocked).
__global__ __launch_bounds__(256, 8) void qff_fused(
    const float* __restrict__ w2,       // (4096, 4) row-major
    const float* __restrict__ wout,     // (1024, 4096) row-major
    const float* __restrict__ params,   // (4,)
    float* __restrict__ o,              // (1024,) in d_ws
    unsigned int* __restrict__ flag,    // 1 u32 in d_ws (memset to 0 each call)
    float* __restrict__ out)            // (16384, 1024)
{
    const int t = threadIdx.x;
    const int bid = blockIdx.x;

    // ---- producer phase: blocks 0..63 compute o[bid*16 .. bid*16+16) ----
    if (bid < NPROD) {
        const int wave = t >> 6;
        const int lane = t & 63;

        const float c0 = cosf(params[0]);
        const float c1 = cosf(params[1]);
        const float c2 = cosf(params[2]);
        const float c3 = cosf(params[3]);
        const float q0 = c1 * c2 * c3;
        const float q1 = c0 * c1;
        const float q2 = q1 * c2;
        const float q3 = q2 * c3;

        const f32x4* w2v = reinterpret_cast<const f32x4*>(w2);
#pragma unroll
        for (int i = 0; i < 4; ++i) {
            const int e = bid * 16 + wave * 4 + i;
            const f32x4* wrow = reinterpret_cast<const f32x4*>(wout + (size_t)e * F_DIM);
            float s = 0.0f;
#pragma unroll
            for (int j = 0; j < 16; ++j) {
                const int g4 = j * 64 + lane;
                f32x4 a  = __builtin_nontemporal_load(&wrow[g4]);  // read-once
                f32x4 r0 = w2v[4 * g4 + 0];                        // L2-resident
                f32x4 r1 = w2v[4 * g4 + 1];
                f32x4 r2 = w2v[4 * g4 + 2];
                f32x4 r3 = w2v[4 * g4 + 3];
                float h0 = fmaxf(r0.x * q0 + r0.y * q1 + r0.z * q2 + r0.w * q3, 0.0f);
                float h1 = fmaxf(r1.x * q0 + r1.y * q1 + r1.z * q2 + r1.w * q3, 0.0f);
                float h2 = fmaxf(r2.x * q0 + r2.y * q1 + r2.z * q2 + r2.w * q3, 0.0f);
                float h3 = fmaxf(r3.x * q0 + r3.y * q1 + r3.z * q2 + r3.w * q3, 0.0f);
                s += a.x * h0 + a.y * h1 + a.z * h2 + a.w * h3;
            }
#pragma unroll
            for (int off = 32; off > 0; off >>= 1) s += __shfl_down(s, off);
            if (lane == 0) o[e] = s;                 // plain store
        }
        __syncthreads();                             // drains block's stores
        if (t == 0) {
            __threadfence();                         // release: writeback to coherence pt
            atomicAdd(flag, 1u);                     // device-scope, ONE per block
        }
    }

    // ---- wait: one lane polls with relaxed loads + sleep backoff ----
    if (t == 0) {
        while (__hip_atomic_load(flag, __ATOMIC_RELAXED, __HIP_MEMORY_SCOPE_AGENT)
               < NPROD) {
            __builtin_amdgcn_s_sleep(16);
        }
        __threadfence();                             // acquire: invalidate stale L1/L2
    }
    __syncthreads();

    // ---- consumer phase: every block broadcasts o into its 8 rows ----
    // plain cached vector load: wave reads 1 KB contiguous, L1-hit after first
    const f32x4 v = reinterpret_cast<const f32x4*>(o)[t];
    f32x4* out4 = reinterpret_cast<f32x4*>(out);
    const size_t base = (size_t)bid * 8 * (E_DIM / 4);
#pragma unroll
    for (int k = 0; k < 8; ++k) {
        // each wave stores 1 KB contiguous; block covers 8 full rows
        __builtin_nontemporal_store(v, &out4[base + k * (E_DIM / 4) + t]);
    }
}

extern "C" void kernel_launch(void* const* d_in, const int* in_sizes, int n_in,
                              void* d_out, int out_size, void* d_ws, size_t ws_size,
                              hipStream_t stream) {
    // inputs (setup_inputs order): x, w1, w2, w_out, params — x/w1 never read.
    const float* w2     = (const float*)d_in[2];
    const float* w_out  = (const float*)d_in[3];
    const float* params = (const float*)d_in[4];
    float* o = (float*)d_ws;                          // 1024 floats
    unsigned int* flag = (unsigned int*)((char*)d_ws + E_DIM * sizeof(float));
    float* out = (float*)d_out;

    hipMemsetAsync(flag, 0, sizeof(unsigned int), stream);   // reset arrivals
    qff_fused<<<NBLK, 256, 0, stream>>>(w2, w_out, params, o, flag, out);
}

// Round 9
// 50.685 us; speedup vs baseline: 64.3756x; 2.3984x over previous
//
#include <hip/hip_runtime.h>
#include <hip/hip_bf16.h>

typedef float f32x4 __attribute__((ext_vector_type(4)));

#define E_DIM 1024    // embed dim (output cols)
#define F_DIM 4096    // ffn dim
#define ROWS  16384   // B*S
#define NCG   16      // column groups: 64 cols (256 B) each
#define NRG   16      // row groups: 1024 rows each

// Sync-free fused kernel (R6 structure, write-granule fixed 64B -> 256B).
// Block (cg, rg) redundantly computes o[64 cols of cg], then streams rows
// [1024*rg, 1024*rg+1024) x 256 B column stripe. No inter-block dependency
// (R3/R7/R8 lesson: any cross-block handshake costs >=100 us on gfx950).
//   o[e] = sum_g w_out[e,g] * relu( sum_f w2[g,f] * q[f] )
// q = analytic 4-qubit circuit expvals; x/w1 are a dead path (RZ on |0> is a
// global phase) -> 64 MiB of input never read.
// XCD locality: bid%8 == cg%8, so all 16 rg-replicas of a column group land
// on one XCD -> its 1 MB w_out slice is read from HBM once, L2 serves reuse.
__global__ __launch_bounds__(256) void qff_fused(
    const float* __restrict__ w2,      // (4096, 4) row-major
    const float* __restrict__ wout,    // (1024, 4096) row-major
    const float* __restrict__ params,  // (4,)
    float* __restrict__ out)           // (16384, 1024)
{
    __shared__ float h[F_DIM];
    __shared__ float o_l[64];

    const int t = threadIdx.x;
    const int wave = t >> 6;
    const int lane = t & 63;
    const int cg = blockIdx.x & (NCG - 1);   // cols [64cg, 64cg+64)
    const int rg = blockIdx.x >> 4;          // rows [1024rg, 1024rg+1024)

    // ---- phase 1: h = relu(w2 @ q) ----
    const float c0 = cosf(params[0]);
    const float c1 = cosf(params[1]);
    const float c2 = cosf(params[2]);
    const float c3 = cosf(params[3]);
    const float q0 = c1 * c2 * c3;
    const float q1 = c0 * c1;
    const float q2 = q1 * c2;
    const float q3 = q2 * c3;

    const f32x4* w2v = reinterpret_cast<const f32x4*>(w2);
    for (int g = t; g < F_DIM; g += 256) {
        f32x4 w = w2v[g];
        float v = w.x * q0 + w.y * q1 + w.z * q2 + w.w * q3;
        h[g] = v > 0.0f ? v : 0.0f;
    }
    __syncthreads();

    // ---- phase 2: o_l[i] = w_out[64cg+i, :] . h, 16 dots per wave ----
    // PLAIN cached loads: the 16x rg-redundancy is the point of L2 reuse.
    const f32x4* h4 = reinterpret_cast<const f32x4*>(h);
    for (int i = wave; i < 64; i += 4) {
        const f32x4* wrow =
            reinterpret_cast<const f32x4*>(wout + (size_t)(cg * 64 + i) * F_DIM);
        float s = 0.0f;
#pragma unroll
        for (int j = 0; j < 16; ++j) {
            f32x4 a = wrow[lane + j * 64];
            f32x4 b = h4[lane + j * 64];
            s += a.x * b.x + a.y * b.y + a.z * b.z + a.w * b.w;
        }
#pragma unroll
        for (int off = 32; off > 0; off >>= 1) s += __shfl_down(s, off);
        if (lane == 0) o_l[i] = s;
    }
    __syncthreads();

    // ---- phase 3: stream 1024 rows x 256 B stripe ----
    // Wave instruction = 4 rows x 256 B contiguous segments (16 lanes each).
    const f32x4 v = reinterpret_cast<const f32x4*>(o_l)[lane & 15];
    const int col4 = cg * 16 + (lane & 15);        // float4 col in [0,256)
    const int rbase = rg * 1024 + wave * 4 + (lane >> 4);
    f32x4* out4 = reinterpret_cast<f32x4*>(out);
#pragma unroll
    for (int k = 0; k < 64; ++k) {
        const int r = rbase + k * 16;
        __builtin_nontemporal_store(v, &out4[(size_t)r * (E_DIM / 4) + col4]);
    }
}

extern "C" void kernel_launch(void* const* d_in, const int* in_sizes, int n_in,
                              void* d_out, int out_size, void* d_ws, size_t ws_size,
                              hipStream_t stream) {
    // inputs (setup_inputs order): x, w1, w2, w_out, params — x/w1 never read.
    const float* w2     = (const float*)d_in[2];
    const float* w_out  = (const float*)d_in[3];
    const float* params = (const float*)d_in[4];
    float* out = (float*)d_out;

    qff_fused<<<NCG * NRG, 256, 0, stream>>>(w2, w_out, params, out);
}

// Round 10
// 25.775 us; speedup vs baseline: 126.5931x; 1.9665x over previous
//
#include <hip/hip_runtime.h>
#include <hip/hip_bf16.h>

typedef float f32x4 __attribute__((ext_vector_type(4)));

#define E_DIM 1024   // embed dim (output cols)
#define F_DIM 4096   // ffn dim
#define ROWS  16384  // B*S

// Kernel 1: o[e] = sum_g w_out[e,g] * relu( sum_f w2[g,f] * q[f] )
// One block per output element e (1024 blocks). 4 waves split the 4096-long
// dot; pure register compute, one __syncthreads for the LDS combine.
// q = analytic 4-qubit circuit expvals; x/w1 are a dead path (RZ on |0> is a
// global phase -> never read, saves 64 MiB of input traffic).
__global__ __launch_bounds__(256) void qff_head(
    const float* __restrict__ w2,      // (4096, 4) row-major
    const float* __restrict__ wout,    // (1024, 4096) row-major
    const float* __restrict__ params,  // (4,)
    float* __restrict__ o)             // (1024,) in d_ws
{
    __shared__ float psum[4];
    const int t = threadIdx.x;
    const int wave = t >> 6;
    const int lane = t & 63;
    const int e = blockIdx.x;

    const float c0 = cosf(params[0]);
    const float c1 = cosf(params[1]);
    const float c2 = cosf(params[2]);
    const float c3 = cosf(params[3]);
    const float q0 = c1 * c2 * c3;
    const float q1 = c0 * c1;
    const float q2 = q1 * c2;
    const float q3 = q2 * c3;

    const f32x4* wrow = reinterpret_cast<const f32x4*>(wout + (size_t)e * F_DIM);
    const f32x4* w2v  = reinterpret_cast<const f32x4*>(w2);

    float s = 0.0f;
#pragma unroll
    for (int j = 0; j < 4; ++j) {
        const int g4 = wave * 256 + j * 64 + lane;  // float4-group in [0,1024)
        f32x4 a  = __builtin_nontemporal_load(&wrow[g4]);  // read-once
        f32x4 r0 = w2v[4 * g4 + 0];                        // w2: 64 KB, L2-resident
        f32x4 r1 = w2v[4 * g4 + 1];
        f32x4 r2 = w2v[4 * g4 + 2];
        f32x4 r3 = w2v[4 * g4 + 3];
        float h0 = fmaxf(r0.x * q0 + r0.y * q1 + r0.z * q2 + r0.w * q3, 0.0f);
        float h1 = fmaxf(r1.x * q0 + r1.y * q1 + r1.z * q2 + r1.w * q3, 0.0f);
        float h2 = fmaxf(r2.x * q0 + r2.y * q1 + r2.z * q2 + r2.w * q3, 0.0f);
        float h3 = fmaxf(r3.x * q0 + r3.y * q1 + r3.z * q2 + r3.w * q3, 0.0f);
        s += a.x * h0 + a.y * h1 + a.z * h2 + a.w * h3;
    }
#pragma unroll
    for (int off = 32; off > 0; off >>= 1) s += __shfl_down(s, off);
    if (lane == 0) psum[wave] = s;
    __syncthreads();
    if (t == 0) o[e] = psum[0] + psum[1] + psum[2] + psum[3];
}

// Kernel 2 (v2): block-contiguous streaming. Block b owns rows [8b, 8b+8)
// and writes its 32 KB region CONTIGUOUSLY (thread t = column-float4 t,
// one full 4 KB row per block-instruction, 8 sequential rows). A/B vs the
// R2-R5 interleaved grid-stride layout (blocks hop 16-32 MB per iteration):
// tests whether per-CU contiguous DRAM streams are what the fill kernel's
// 6.8 TB/s depends on.
__global__ __launch_bounds__(256) void qff_bcast(
    const float* __restrict__ o, float* __restrict__ out)
{
    const int t = threadIdx.x;
    const f32x4 v = reinterpret_cast<const f32x4*>(o)[t];   // col-float4 t
    f32x4* out4 = reinterpret_cast<f32x4*>(out);
    const size_t base = (size_t)blockIdx.x * 8 * (E_DIM / 4);
#pragma unroll
    for (int k = 0; k < 8; ++k) {
        __builtin_nontemporal_store(v, &out4[base + k * (E_DIM / 4) + t]);
    }
}

extern "C" void kernel_launch(void* const* d_in, const int* in_sizes, int n_in,
                              void* d_out, int out_size, void* d_ws, size_t ws_size,
                              hipStream_t stream) {
    // inputs (setup_inputs order): x, w1, w2, w_out, params — x/w1 never read.
    const float* w2     = (const float*)d_in[2];
    const float* w_out  = (const float*)d_in[3];
    const float* params = (const float*)d_in[4];
    float* o   = (float*)d_ws;    // 1024 floats of scratch, rewritten every call
    float* out = (float*)d_out;

    qff_head<<<E_DIM, 256, 0, stream>>>(w2, w_out, params, o);

    // 2048 blocks x 8 rows = 16384 rows; each block streams 32 KB contiguous
    qff_bcast<<<ROWS / 8, 256, 0, stream>>>(o, out);
}